// Round 3
// baseline (2629.428 us; speedup 1.0000x reference)
//
#include <hip/hip_runtime.h>

// Problem constants: B=1048576, T=11, F=3, H=11, C=7
#define TT 11
#define FF 3
#define HH 11
#define CC 7
#define TF 33      // T*F
#define BLOCK 256
#define XDW 22     // dwords per batch element in LDS x-stage (11 t * 2 dwords)

typedef _Float16 h2 __attribute__((ext_vector_type(2)));  // 4 bytes: 2 x f16

// workspace dword offsets (identical layout to the proven round-0 kernel)
#define WS_G   0      // [11][28]: per-gate block (see prep_weights)
#define WS_D   308    // [11][7][6]: dense f16 pairs per t, per col
#define WS_DB  770    // [7] f32 dense bias
#define WS_TOT 777    // total dwords

__device__ __forceinline__ float fdot2(h2 a, h2 b, float c) {
    // v_dot2_f32_f16: fp32 accumulate
    return __builtin_amdgcn_fdot2(a, b, c, false);
}

__device__ __forceinline__ float fast_sigmoid(float a) {
    float t = __builtin_amdgcn_exp2f(-1.44269504088896340736f * a);
    return __builtin_amdgcn_rcpf(1.0f + t);
}
// tanh(a) = 2*sigmoid(2a) - 1 ; monotone-safe at +-inf, no NaN
__device__ __forceinline__ float fast_tanh(float a) {
    float t = __builtin_amdgcn_exp2f(-2.88539008177792681472f * a);
    return fmaf(2.0f, __builtin_amdgcn_rcpf(1.0f + t), -1.0f);
}

__global__ void prep_weights(const float* __restrict__ k,
                             const float* __restrict__ rk,
                             const float* __restrict__ bias,
                             const float* __restrict__ dw,
                             const float* __restrict__ db,
                             float* __restrict__ ws) {
    const int tid = threadIdx.x;
    // Per-gate 28-dword block: dot2-ready f16 pairs + f32 biases.
    //  [0..5]  z recurrent pairs (h0,h1)..(h10,0)
    //  [6]     z input pair (k0,k1)   [7] (k2, 0)
    //  [8]     z bias f32 (in+rec folded)
    //  [9..14] r recurrent pairs  [15],[16] r input  [17] r bias f32
    //  [18..23] h recurrent pairs
    //  [24],[25] h input pairs
    //  [26]    h recurrent bias f32 (inside r*)   [27] h input bias f32
    if (tid < HH) {
        const int j = tid;
        float* g = ws + WS_G + j * 28;
        h2* gp = (h2*)g;
        const int cz = j, cr = HH + j, ch = 2 * HH + j;
        #pragma unroll
        for (int p = 0; p < 6; ++p) {
            const int i0 = 2 * p, i1 = 2 * p + 1;
            h2 vz = {(_Float16)rk[i0 * TF + cz],
                     (_Float16)((i1 < HH) ? rk[i1 * TF + cz] : 0.0f)};
            gp[p] = vz;
            h2 vr = {(_Float16)rk[i0 * TF + cr],
                     (_Float16)((i1 < HH) ? rk[i1 * TF + cr] : 0.0f)};
            gp[9 + p] = vr;
            h2 vh = {(_Float16)rk[i0 * TF + ch],
                     (_Float16)((i1 < HH) ? rk[i1 * TF + ch] : 0.0f)};
            gp[18 + p] = vh;
        }
        h2 iz0 = {(_Float16)k[0 * TF + cz], (_Float16)k[1 * TF + cz]};
        h2 iz1 = {(_Float16)k[2 * TF + cz], (_Float16)0.0f};
        gp[6] = iz0; gp[7] = iz1;
        g[8] = bias[cz] + bias[TF + cz];
        h2 ir0 = {(_Float16)k[0 * TF + cr], (_Float16)k[1 * TF + cr]};
        h2 ir1 = {(_Float16)k[2 * TF + cr], (_Float16)0.0f};
        gp[15] = ir0; gp[16] = ir1;
        g[17] = bias[cr] + bias[TF + cr];
        h2 ih0 = {(_Float16)k[0 * TF + ch], (_Float16)k[1 * TF + ch]};
        h2 ih1 = {(_Float16)k[2 * TF + ch], (_Float16)0.0f};
        gp[24] = ih0; gp[25] = ih1;
        g[26] = bias[TF + ch];  // recurrent bias (multiplied by r)
        g[27] = bias[ch];       // input bias
    }
    // dense: pairs along j within each t, per output col c
    for (int idx = tid; idx < TT * CC; idx += BLOCK) {
        const int t = idx / CC, c = idx % CC;
        h2* d = (h2*)(ws + WS_D + t * 42 + c * 6);
        #pragma unroll
        for (int p = 0; p < 6; ++p) {
            const int j0 = 2 * p, j1 = 2 * p + 1;
            h2 v = {(_Float16)dw[(t * HH + j0) * CC + c],
                    (_Float16)((j1 < HH) ? dw[(t * HH + j1) * CC + c] : 0.0f)};
            d[p] = v;
        }
    }
    if (tid < CC) ws[WS_DB + tid] = db[tid];
}

__global__ __launch_bounds__(BLOCK, 6) void gru_main(
    const float* __restrict__ x,   // [B, T*F] f32
    const float* __restrict__ ws,  // packed weights (copied to LDS)
    float* __restrict__ out,       // [B, C]
    int Bt)
{
    __shared__ unsigned int sx[BLOCK * XDW];  // 22528 B x-stage
    __shared__ float swt[WS_TOT];             // 3108 B weights: ds_read w/ imm offsets
    const int tid = threadIdx.x;
    const long long base = (long long)blockIdx.x * BLOCK;

    // ---- one-time weight stage: global -> LDS (coalesced, 4 iters) ----
    for (int i = tid; i < WS_TOT; i += BLOCK) swt[i] = ws[i];

    // ---- coalesced stage of x, converted+packed to f16 pairs (x0,x1),(x2,0) ----
    {
        const long long gbase = base * TF;
        const long long gmax = (long long)Bt * TF;
        unsigned short* sx16 = (unsigned short*)sx;
        #pragma unroll
        for (int i = 0; i < TF; ++i) {
            const int e = tid + i * BLOCK;           // flat idx in block tile
            const long long g = gbase + e;
            const float v = (g < gmax) ? x[g] : 0.0f;
            const int b = e / TF, r = e % TF;        // compiler emits magic-mul
            const int t = r / FF, s = r % FF;
            const unsigned short hv =
                __builtin_bit_cast(unsigned short, (_Float16)v);
            if (s == 2)
                sx[b * XDW + 2 * t + 1] = (unsigned int)hv;  // (x2, 0): hi half zeroed
            else
                sx16[(b * XDW + 2 * t) * 2 + s] = hv;        // byte-masked b16 write
        }
    }
    __syncthreads();

    const uint2* xrow = (const uint2*)(sx + tid * XDW);

    float hf[HH];
    #pragma unroll
    for (int j = 0; j < HH; ++j) hf[j] = 0.0f;
    h2 hp[6];
    #pragma unroll
    for (int p = 0; p < 6; ++p) { h2 zz = {(_Float16)0.0f, (_Float16)0.0f}; hp[p] = zz; }
    float lg[CC];
    #pragma unroll
    for (int c = 0; c < CC; ++c) lg[c] = swt[WS_DB + c];

    #pragma unroll 1
    for (int t = 0; t < TT; ++t) {
        const uint2 xw = xrow[t];                 // one ds_read_b64
        const h2 xp0 = __builtin_bit_cast(h2, xw.x);
        const h2 xp1 = __builtin_bit_cast(h2, xw.y);

        #pragma unroll
        for (int j = 0; j < HH; ++j) {
            const float* g = swt + WS_G + j * 28;   // LDS: imm-offset ds_reads
            const h2* gp = (const h2*)g;
            float az = g[8];
            float ar = g[17];
            float rh = g[26];
            float xh = g[27];
            #pragma unroll
            for (int p = 0; p < 6; ++p) {
                az = fdot2(hp[p], gp[p], az);
                ar = fdot2(hp[p], gp[9 + p], ar);
                rh = fdot2(hp[p], gp[18 + p], rh);
            }
            az = fdot2(xp0, gp[6], az);   az = fdot2(xp1, gp[7], az);
            ar = fdot2(xp0, gp[15], ar);  ar = fdot2(xp1, gp[16], ar);
            xh = fdot2(xp0, gp[24], xh);  xh = fdot2(xp1, gp[25], xh);
            const float z = fast_sigmoid(az);
            const float r = fast_sigmoid(ar);
            const float hh = fast_tanh(fmaf(r, rh, xh));
            hf[j] = hh + z * (hf[j] - hh);   // z*h + (1-z)*hh
        }
        // repack h -> f16 pairs (v_cvt_pkrtz x6)
        #pragma unroll
        for (int p = 0; p < 5; ++p) {
            h2 v = {(_Float16)hf[2 * p], (_Float16)hf[2 * p + 1]};
            hp[p] = v;
        }
        { h2 v = {(_Float16)hf[10], (_Float16)0.0f}; hp[5] = v; }

        // fused dense: logits += h_t @ dw_t (fp32 accum via dot2)
        const h2* dd = (const h2*)(swt + WS_D + t * 42);
        #pragma unroll
        for (int c = 0; c < CC; ++c) {
            float acc = lg[c];
            #pragma unroll
            for (int p = 0; p < 6; ++p) acc = fdot2(hp[p], dd[c * 6 + p], acc);
            lg[c] = acc;
        }
    }

    // ---- softmax ----
    float m = lg[0];
    #pragma unroll
    for (int c = 1; c < CC; ++c) m = fmaxf(m, lg[c]);
    float s = 0.0f;
    float e[CC];
    #pragma unroll
    for (int c = 0; c < CC; ++c) {
        e[c] = __builtin_amdgcn_exp2f((lg[c] - m) * 1.44269504088896340736f);
        s += e[c];
    }
    const float inv = __builtin_amdgcn_rcpf(s);

    // ---- staged coalesced writeback (reuse sx as float buffer) ----
    __syncthreads();
    float* sf = (float*)sx;
    #pragma unroll
    for (int c = 0; c < CC; ++c) sf[tid * CC + c] = e[c] * inv;  // stride 7: conflict-free
    __syncthreads();
    {
        const long long obase = base * CC;
        const long long omax = (long long)Bt * CC;
        #pragma unroll
        for (int i = 0; i < CC; ++i) {
            long long g = obase + tid + i * BLOCK;
            if (g < omax) out[g] = sf[tid + i * BLOCK];
        }
    }
}

extern "C" void kernel_launch(void* const* d_in, const int* in_sizes, int n_in,
                              void* d_out, int out_size, void* d_ws, size_t ws_size,
                              hipStream_t stream) {
    const float* x  = (const float*)d_in[0];
    const float* k  = (const float*)d_in[1];
    const float* rk = (const float*)d_in[2];
    const float* bi = (const float*)d_in[3];
    const float* dw = (const float*)d_in[4];
    const float* db = (const float*)d_in[5];
    float* out = (float*)d_out;
    float* ws  = (float*)d_ws;

    const int Bt = in_sizes[0] / TF;  // 1048576
    prep_weights<<<1, BLOCK, 0, stream>>>(k, rk, bi, dw, db, ws);
    const int grid = (Bt + BLOCK - 1) / BLOCK;
    gru_main<<<grid, BLOCK, 0, stream>>>(x, ws, out, Bt);
}

// Round 4
// 351.104 us; speedup vs baseline: 7.4890x; 7.4890x over previous
//
#include <hip/hip_runtime.h>

// Problem constants: B=1048576, T=11, F=3, H=11, C=7
#define TT 11
#define FF 3
#define HH 11
#define CC 7
#define TF 33      // T*F
#define BLOCK 256
#define L2E 1.44269504088896340736f

typedef _Float16 h4 __attribute__((ext_vector_type(4)));   // one MFMA A/B fragment (2 VGPRs)
typedef float f4 __attribute__((ext_vector_type(4)));      // one MFMA C/D fragment
typedef unsigned int u2 __attribute__((ext_vector_type(2)));

// ws layout (dwords):
//  [0..511]    gate A-fragments  [4 gates][64 lanes][2 dwords]  (f16 x4 per lane)
//  [512..1919] dense A-fragments [11 t   ][64 lanes][2 dwords]
#define WS_GA 0
#define WS_DA 512
#define WS_TOT 1920

__device__ __forceinline__ float fast_sigmoid(float a) {
    float t = __builtin_amdgcn_exp2f(-L2E * a);
    return __builtin_amdgcn_rcpf(1.0f + t);
}
// tanh(a) = 2*sigmoid(2a) - 1
__device__ __forceinline__ float fast_tanh(float a) {
    float t = __builtin_amdgcn_exp2f(-2.0f * L2E * a);
    return fmaf(2.0f, __builtin_amdgcn_rcpf(1.0f + t), -1.0f);
}

// Augmented weight matrix value, transposed form A'[row=n(gate out)][k]:
//  k=0..10 -> h_k coefficient, k=11..13 -> x_{k-11} coefficient, k=14 -> bias (B row 14 = 1.0), k=15 -> 0
__device__ __forceinline__ float gate_val(int g, int k, int n,
        const float* rk, const float* kk, const float* bias) {
    if (n >= HH) return 0.0f;
    if (g == 0 || g == 1) {            // z, r: full augmented row
        const int col = (g == 0 ? 0 : HH) + n;
        if (k < HH) return rk[k * TF + col];
        if (k < 14) return kk[(k - 11) * TF + col];
        if (k == 14) return bias[col] + bias[TF + col];
        return 0.0f;
    }
    const int col = 2 * HH + n;
    if (g == 2) {                      // rh: recurrent candidate part (+ recurrent bias)
        if (k < HH) return rk[k * TF + col];
        if (k == 14) return bias[TF + col];
        return 0.0f;
    }
    // g == 3, xh: input candidate part (+ input bias)
    if (k >= 11 && k < 14) return kk[(k - 11) * TF + col];
    if (k == 14) return bias[col];
    return 0.0f;
}

__global__ void prep_weights(const float* __restrict__ k,
                             const float* __restrict__ rk,
                             const float* __restrict__ bias,
                             const float* __restrict__ dw,
                             const float* __restrict__ db,
                             float* __restrict__ ws) {
    const int tid = threadIdx.x;
    unsigned int* wsu = (unsigned int*)ws;
    // gate A-frags: one (gate, lane) pair per thread (4*64 = 256)
    {
        const int g = tid >> 6, l = tid & 63;
        const int n = l & 15, kb = 4 * (l >> 4);
        unsigned short h[4];
        #pragma unroll
        for (int i = 0; i < 4; ++i) {
            const float v = gate_val(g, kb + i, n, rk, k, bias);
            h[i] = __builtin_bit_cast(unsigned short, (_Float16)v);
        }
        wsu[WS_GA + (g * 64 + l) * 2]     = h[0] | ((unsigned int)h[1] << 16);
        wsu[WS_GA + (g * 64 + l) * 2 + 1] = h[2] | ((unsigned int)h[3] << 16);
    }
    // dense A-frags: A'_t[row=c][k] = dw_t[k][c] for k<11; k=14,t=0 -> db[c] (ones-row trick)
    for (int idx = tid; idx < TT * 64; idx += BLOCK) {
        const int t = idx >> 6, l = idx & 63;
        const int c = l & 15, kb = 4 * (l >> 4);
        unsigned short h[4];
        #pragma unroll
        for (int i = 0; i < 4; ++i) {
            const int kk2 = kb + i;
            float v = 0.0f;
            if (c < CC) {
                if (kk2 < HH) v = dw[(t * HH + kk2) * CC + c];
                else if (kk2 == 14 && t == 0) v = db[c];
            }
            h[i] = __builtin_bit_cast(unsigned short, (_Float16)v);
        }
        wsu[WS_DA + idx * 2]     = h[0] | ((unsigned int)h[1] << 16);
        wsu[WS_DA + idx * 2 + 1] = h[2] | ((unsigned int)h[3] << 16);
    }
}

__global__ __launch_bounds__(BLOCK, 5) void gru_main(
    const float* __restrict__ x,   // [B, T*F] f32
    const float* __restrict__ ws,  // fragment-ordered weights
    float* __restrict__ out,       // [B, C]
    int Bt)
{
    // per (b,t): dword0 = f16(x1,x2) ; dword1 = (0 | x0<<16)
    __shared__ unsigned int sxb[BLOCK * TT * 2];   // 22528 B
    __shared__ float sda[TT * 64 * 2];             // 5632 B dense A-frags
    const int tid = threadIdx.x;
    const long long base = (long long)blockIdx.x * BLOCK;

    // dense A-frags -> LDS (coalesced, once)
    for (int i = tid; i < TT * 128; i += BLOCK) sda[i] = ws[WS_DA + i];

    const int lane = tid & 63, wave = tid >> 6;
    // gate A-frags -> registers (8 VGPRs total; all GRU weights+biases)
    const h4* gfp = (const h4*)ws;
    const h4 Az  = gfp[lane];
    const h4 Ar  = gfp[64 + lane];
    const h4 Arh = gfp[128 + lane];
    const h4 Axh = gfp[192 + lane];

    // ---- coalesced x stage, f16-packed in B-fragment-friendly form ----
    {
        const long long gbase = base * TF;
        const long long gmax = (long long)Bt * TF;
        unsigned short* s16 = (unsigned short*)sxb;
        #pragma unroll
        for (int i = 0; i < TF; ++i) {
            const int e = tid + i * BLOCK;
            const long long g = gbase + e;
            const float v = (g < gmax) ? x[g] : 0.0f;
            const int b = e / TF, r = e % TF;
            const int t = r / FF, s = r % FF;
            const unsigned short hv = __builtin_bit_cast(unsigned short, (_Float16)v);
            const int dw0 = (b * TT + t) * 2;
            if (s == 0) sxb[dw0 + 1] = ((unsigned int)hv) << 16;   // (0, x0)
            else        s16[dw0 * 2 + (s - 1)] = hv;               // (x1, x2)
        }
    }
    __syncthreads();

    const int q = lane & 15, p = lane >> 4;

    // Per-tile state: hD[k][r] = h[j = 4p+r][b = tile_base + q]  (D-fragment layout)
    float hD[4][4];
    f4 dC[4];
    #pragma unroll
    for (int k2 = 0; k2 < 4; ++k2) {
        dC[k2] = (f4){0.f, 0.f, 0.f, 0.f};
        #pragma unroll
        for (int r = 0; r < 4; ++r) hD[k2][r] = 0.0f;
    }

    // per-lane x read base: lanes p==2 read dword1 (x0), others dword0 (x1,x2)
    const int xbase = wave * (64 * TT * 2) + q * (TT * 2) + ((p == 2) ? 1 : 0);
    const f4 zf4 = {0.f, 0.f, 0.f, 0.f};

    #pragma unroll 1
    for (int t = 0; t < TT + 1; ++t) {
        const int tx = (t < TT) ? t : (TT - 1);   // t==11: x slots multiplied by 0 in dense A
        // ---- build B fragments: k=0..10 from hD (lane-local pass-through!), 11..13 x, 14 one ----
        h4 Bv[4];
        #pragma unroll
        for (int k2 = 0; k2 < 4; ++k2) {
            const unsigned int xw = sxb[xbase + tx * 2 + k2 * (16 * TT * 2)];
            // RTE f16 packs of this lane's 4 h values
            const unsigned int pk01 =
                (unsigned int)__builtin_bit_cast(unsigned short, (_Float16)hD[k2][0]) |
                ((unsigned int)__builtin_bit_cast(unsigned short, (_Float16)hD[k2][1]) << 16);
            const unsigned int pk23 =
                (unsigned int)__builtin_bit_cast(unsigned short, (_Float16)hD[k2][2]) |
                ((unsigned int)__builtin_bit_cast(unsigned short, (_Float16)hD[k2][3]) << 16);
            // p==2 lane: elems (h8,h9),(h10,x0); p==3 lane: (x1,x2),(1.0,0)
            const unsigned int c2 =
                (unsigned int)__builtin_bit_cast(unsigned short, (_Float16)hD[k2][2]) | xw;
            const unsigned int b0 = (p == 3) ? xw : pk01;
            const unsigned int b1 = (p <= 1) ? pk23 : ((p == 2) ? c2 : 0x00003C00u);
            const u2 bb = {b0, b1};
            Bv[k2] = __builtin_bit_cast(h4, bb);
        }
        // ---- fused dense: logits += dw_{t-1}^T · h_{t-1} (B rows >=11 zeroed by A) ----
        if (t) {
            const h4 dA = *(const h4*)(sda + (t - 1) * 128 + lane * 2);
            #pragma unroll
            for (int k2 = 0; k2 < 4; ++k2)
                dC[k2] = __builtin_amdgcn_mfma_f32_16x16x16f16(dA, Bv[k2], dC[k2], 0, 0, 0);
        }
        // ---- gate MFMAs + lane-local nonlinearity ----
        if (t < TT) {
            #pragma unroll
            for (int k2 = 0; k2 < 4; ++k2) {
                f4 vz  = __builtin_amdgcn_mfma_f32_16x16x16f16(Az,  Bv[k2], zf4, 0, 0, 0);
                f4 vr  = __builtin_amdgcn_mfma_f32_16x16x16f16(Ar,  Bv[k2], zf4, 0, 0, 0);
                f4 vrh = __builtin_amdgcn_mfma_f32_16x16x16f16(Arh, Bv[k2], zf4, 0, 0, 0);
                f4 vxh = __builtin_amdgcn_mfma_f32_16x16x16f16(Axh, Bv[k2], zf4, 0, 0, 0);
                #pragma unroll
                for (int r = 0; r < 4; ++r) {
                    const float z  = fast_sigmoid(vz[r]);
                    const float rr = fast_sigmoid(vr[r]);
                    const float hh = fast_tanh(fmaf(rr, vrh[r], vxh[r]));
                    hD[k2][r] = hh + z * (hD[k2][r] - hh);   // z*h + (1-z)*hh
                }
            }
        }
    }

    // ---- softmax over c per batch: lanes (0,q)<->(1,q) hold c=0..3 / 4..6 ----
    __syncthreads();           // everyone done reading sxb; reuse it as output stage
    float* sf = (float*)sxb;
    #pragma unroll
    for (int k2 = 0; k2 < 4; ++k2) {
        const float d0 = dC[k2][0], d1 = dC[k2][1], d2 = dC[k2][2], d3 = dC[k2][3];
        float mloc = fmaxf(fmaxf(d0, d1), d2);
        if (p == 0) mloc = fmaxf(mloc, d3);           // p==1: c=7 is padding, exclude
        const float m = fmaxf(mloc, __shfl_xor(mloc, 16, 64));
        const float e0 = __builtin_amdgcn_exp2f((d0 - m) * L2E);
        const float e1 = __builtin_amdgcn_exp2f((d1 - m) * L2E);
        const float e2 = __builtin_amdgcn_exp2f((d2 - m) * L2E);
        const float e3 = (p == 0) ? __builtin_amdgcn_exp2f((d3 - m) * L2E) : 0.0f;
        const float sl = e0 + e1 + e2 + e3;
        const float ssum = sl + __shfl_xor(sl, 16, 64);
        const float inv = __builtin_amdgcn_rcpf(ssum);
        if (p < 2) {
            const int bL = wave * 64 + k2 * 16 + q;
            float* dst = sf + bL * CC + p * 4;
            dst[0] = e0 * inv; dst[1] = e1 * inv; dst[2] = e2 * inv;
            if (p == 0) dst[3] = e3 * inv;
        }
    }
    __syncthreads();
    // ---- coalesced writeback ----
    {
        const long long obase = base * CC;
        const long long omax = (long long)Bt * CC;
        #pragma unroll
        for (int i = 0; i < CC; ++i) {
            const long long g = obase + tid + i * BLOCK;
            if (g < omax) out[g] = sf[tid + i * BLOCK];
        }
    }
}

extern "C" void kernel_launch(void* const* d_in, const int* in_sizes, int n_in,
                              void* d_out, int out_size, void* d_ws, size_t ws_size,
                              hipStream_t stream) {
    const float* x  = (const float*)d_in[0];
    const float* k  = (const float*)d_in[1];
    const float* rk = (const float*)d_in[2];
    const float* bi = (const float*)d_in[3];
    const float* dw = (const float*)d_in[4];
    const float* db = (const float*)d_in[5];
    float* out = (float*)d_out;
    float* ws  = (float*)d_ws;

    const int Bt = in_sizes[0] / TF;  // 1048576
    prep_weights<<<1, BLOCK, 0, stream>>>(k, rk, bi, dw, db, ws);
    const int grid = (Bt + BLOCK - 1) / BLOCK;
    gru_main<<<grid, BLOCK, 0, stream>>>(x, ws, out, Bt);
}

// Round 5
// 326.852 us; speedup vs baseline: 8.0447x; 1.0742x over previous
//
#include <hip/hip_runtime.h>

// Problem constants: B=1048576, T=11, F=3, H=11, C=7
#define TT 11
#define FF 3
#define HH 11
#define CC 7
#define TF 33      // T*F
#define BLOCK 256
#define L2E 1.44269504088896340736f

typedef _Float16 h4 __attribute__((ext_vector_type(4)));   // one MFMA A/B fragment (2 VGPRs)
typedef float f4 __attribute__((ext_vector_type(4)));      // one MFMA C/D fragment
typedef unsigned int u2 __attribute__((ext_vector_type(2)));

// ws layout (dwords):
//  [0..511]    gate A-fragments  [4 gates][64 lanes][2 dwords]  (PRE-SCALED by -log2e / -2log2e)
//  [512..1919] dense A-fragments [11 t   ][64 lanes][2 dwords]
#define WS_GA 0
#define WS_DA 512
#define WS_TOT 1920

// Augmented weight matrix value, transposed form A'[row=n(gate out)][k]:
//  k=0..10 -> h_k coefficient, k=11..13 -> x_{k-11} coefficient, k=14 -> bias (B row 14 = 1.0), k=15 -> 0
__device__ __forceinline__ float gate_val(int g, int k, int n,
        const float* rk, const float* kk, const float* bias) {
    if (n >= HH) return 0.0f;
    if (g == 0 || g == 1) {            // z, r: full augmented row
        const int col = (g == 0 ? 0 : HH) + n;
        if (k < HH) return rk[k * TF + col];
        if (k < 14) return kk[(k - 11) * TF + col];
        if (k == 14) return bias[col] + bias[TF + col];
        return 0.0f;
    }
    const int col = 2 * HH + n;
    if (g == 2) {                      // rh: recurrent candidate part (+ recurrent bias)
        if (k < HH) return rk[k * TF + col];
        if (k == 14) return bias[TF + col];
        return 0.0f;
    }
    // g == 3, xh: input candidate part (+ input bias)
    if (k >= 11 && k < 14) return kk[(k - 11) * TF + col];
    if (k == 14) return bias[col];
    return 0.0f;
}

__global__ void prep_weights(const float* __restrict__ k,
                             const float* __restrict__ rk,
                             const float* __restrict__ bias,
                             const float* __restrict__ dw,
                             const float* __restrict__ db,
                             float* __restrict__ ws) {
    const int tid = threadIdx.x;
    unsigned int* wsu = (unsigned int*)ws;
    // gate A-frags: one (gate, lane) pair per thread (4*64 = 256)
    // Pre-scale: z,r rows by -log2e (so exp2(az') = e^{-az}); rh,xh rows by -2log2e.
    {
        const int g = tid >> 6, l = tid & 63;
        const int n = l & 15, kb = 4 * (l >> 4);
        const float scale = (g < 2) ? -L2E : (-2.0f * L2E);
        unsigned short h[4];
        #pragma unroll
        for (int i = 0; i < 4; ++i) {
            const float v = gate_val(g, kb + i, n, rk, k, bias) * scale;
            h[i] = __builtin_bit_cast(unsigned short, (_Float16)v);
        }
        wsu[WS_GA + (g * 64 + l) * 2]     = h[0] | ((unsigned int)h[1] << 16);
        wsu[WS_GA + (g * 64 + l) * 2 + 1] = h[2] | ((unsigned int)h[3] << 16);
    }
    // dense A-frags: A'_t[row=c][k] = dw_t[k][c] for k<11; k=14,t=0 -> db[c] (ones-row trick)
    for (int idx = tid; idx < TT * 64; idx += BLOCK) {
        const int t = idx >> 6, l = idx & 63;
        const int c = l & 15, kb = 4 * (l >> 4);
        unsigned short h[4];
        #pragma unroll
        for (int i = 0; i < 4; ++i) {
            const int kk2 = kb + i;
            float v = 0.0f;
            if (c < CC) {
                if (kk2 < HH) v = dw[(t * HH + kk2) * CC + c];
                else if (kk2 == 14 && t == 0) v = db[c];
            }
            h[i] = __builtin_bit_cast(unsigned short, (_Float16)v);
        }
        wsu[WS_DA + idx * 2]     = h[0] | ((unsigned int)h[1] << 16);
        wsu[WS_DA + idx * 2 + 1] = h[2] | ((unsigned int)h[3] << 16);
    }
}

__device__ __forceinline__ unsigned int pkf16(float a, float b) {
    return (unsigned int)__builtin_bit_cast(unsigned short, (_Float16)a) |
           ((unsigned int)__builtin_bit_cast(unsigned short, (_Float16)b) << 16);
}

__global__ __launch_bounds__(BLOCK, 7) void gru_main(
    const float* __restrict__ x,   // [B, T*F] f32
    const float* __restrict__ ws,  // fragment-ordered weights
    float* __restrict__ out,       // [B, C]
    int Bt)
{
    // compact x stage: 6 B per (b,t) -> total 16896 B; + dense frags 5632 B = 22528 B -> 7 blocks/CU
    __shared__ unsigned int   sxA[BLOCK * TT];    // (x1,x2) f16 pair       11264 B
    __shared__ unsigned short sxB[BLOCK * TT];    // x0 f16                  5632 B
    __shared__ float sda[TT * 128];               // dense A-frags           5632 B
    const int tid = threadIdx.x;
    const long long base = (long long)blockIdx.x * BLOCK;

    // dense A-frags -> LDS (coalesced, once)
    for (int i = tid; i < TT * 128; i += BLOCK) sda[i] = ws[WS_DA + i];

    const int lane = tid & 63, wave = tid >> 6;
    // gate A-frags -> registers (8 VGPRs total; all GRU weights+biases, pre-scaled)
    const h4* gfp = (const h4*)ws;
    const h4 Az  = gfp[lane];
    const h4 Ar  = gfp[64 + lane];
    const h4 Arh = gfp[128 + lane];
    const h4 Axh = gfp[192 + lane];

    // ---- coalesced x stage, f16-packed compact ----
    {
        const long long gbase = base * TF;
        const long long gmax = (long long)Bt * TF;
        unsigned short* sxA16 = (unsigned short*)sxA;
        #pragma unroll
        for (int i = 0; i < TF; ++i) {
            const int e = tid + i * BLOCK;
            const long long g = gbase + e;
            const float v = (g < gmax) ? x[g] : 0.0f;
            const int b = e / TF, r = e % TF;
            const int t = r / FF, s = r % FF;
            const unsigned short hv = __builtin_bit_cast(unsigned short, (_Float16)v);
            if (s == 0) sxB[b * TT + t] = hv;                   // x0
            else        sxA16[(b * TT + t) * 2 + (s - 1)] = hv; // (x1,x2)
        }
    }
    __syncthreads();

    const int q = lane & 15, p = lane >> 4;

    // Per-tile state: hD[k2][r] = h[j = 4p+r][b = 16*k2 + q]  (D-fragment layout)
    float hD[4][4];
    f4 dC[4];
    #pragma unroll
    for (int k2 = 0; k2 < 4; ++k2) {
        dC[k2] = (f4){0.f, 0.f, 0.f, 0.f};
        #pragma unroll
        for (int r = 0; r < 4; ++r) hD[k2][r] = 0.0f;
    }

    const int ibq = (wave * 64 + q) * TT;   // per-lane x index base
    const f4 zf4 = {0.f, 0.f, 0.f, 0.f};

    #pragma unroll 1
    for (int t = 0; t < TT + 1; ++t) {
        const int tx = (t < TT) ? t : (TT - 1);   // t==11: x slots multiplied by 0 in dense A
        // ---- build B fragments: k=0..10 from hD (lane-local pass-through), 11..13 x, 14 one ----
        h4 Bv[4];
        #pragma unroll
        for (int k2 = 0; k2 < 4; ++k2) {
            const int xi = ibq + k2 * (16 * TT) + tx;
            unsigned int xw = 0;
            if (p == 3)      xw = sxA[xi];                              // (x1,x2)
            else if (p == 2) xw = ((unsigned int)sxB[xi]) << 16;        // (-,x0)
            const unsigned int pk01 = pkf16(hD[k2][0], hD[k2][1]);
            const unsigned int pk23 = pkf16(hD[k2][2], hD[k2][3]);
            // p==2 lane: elems (h8,h9),(h10,x0); p==3 lane: (x1,x2),(1.0,0)
            const unsigned int c2 = (pk23 & 0xFFFFu) | xw;
            const unsigned int b0 = (p == 3) ? xw : pk01;
            const unsigned int b1 = (p <= 1) ? pk23 : ((p == 2) ? c2 : 0x00003C00u);
            const u2 bb = {b0, b1};
            Bv[k2] = __builtin_bit_cast(h4, bb);
        }
        // ---- fused dense: logits += dw_{t-1}^T · h_{t-1} (B rows >=11 zeroed by A) ----
        if (t) {
            const h4 dA = *(const h4*)(sda + (t - 1) * 128 + lane * 2);
            #pragma unroll
            for (int k2 = 0; k2 < 4; ++k2)
                dC[k2] = __builtin_amdgcn_mfma_f32_16x16x16f16(dA, Bv[k2], dC[k2], 0, 0, 0);
        }
        // ---- gate MFMAs + fused nonlinearity ----
        // A pre-scaled: vz = -az*log2e, vv = -ar*log2e, vrh/vxh = -2log2e * (rh / xh)
        // tz=e^{-az}, tv=e^{-ar}, r=1/(1+tv), tu=e^{-2(r*rh+xh)}
        // h' = z*h + (1-z)*tanh(..) = [(h+tz) + tu*(h-tz)] / [(1+tz)(1+tu)]
        if (t < TT) {
            #pragma unroll
            for (int k2 = 0; k2 < 4; ++k2) {
                f4 vz  = __builtin_amdgcn_mfma_f32_16x16x16f16(Az,  Bv[k2], zf4, 0, 0, 0);
                f4 vv  = __builtin_amdgcn_mfma_f32_16x16x16f16(Ar,  Bv[k2], zf4, 0, 0, 0);
                f4 vrh = __builtin_amdgcn_mfma_f32_16x16x16f16(Arh, Bv[k2], zf4, 0, 0, 0);
                f4 vxh = __builtin_amdgcn_mfma_f32_16x16x16f16(Axh, Bv[k2], zf4, 0, 0, 0);
                #pragma unroll
                for (int r = 0; r < 4; ++r) {
                    const float tz = __builtin_amdgcn_exp2f(vz[r]);
                    const float tv = __builtin_amdgcn_exp2f(vv[r]);
                    const float rr = __builtin_amdgcn_rcpf(1.0f + tv);
                    const float tu = __builtin_amdgcn_exp2f(fmaf(rr, vrh[r], vxh[r]));
                    const float hp = hD[k2][r];
                    const float num = fmaf(tu, hp - tz, hp + tz);
                    const float den = (1.0f + tz) * (1.0f + tu);
                    hD[k2][r] = num * __builtin_amdgcn_rcpf(den);
                }
            }
        }
    }

    // ---- softmax over c per batch: lanes (0,q)<->(1,q) hold c=0..3 / 4..6 ----
    __syncthreads();           // everyone done reading x stage; reuse sxA as output stage
    float* sf = (float*)sxA;   // needs 7168 B <= 11264 B
    #pragma unroll
    for (int k2 = 0; k2 < 4; ++k2) {
        const float d0 = dC[k2][0], d1 = dC[k2][1], d2 = dC[k2][2], d3 = dC[k2][3];
        float mloc = fmaxf(fmaxf(d0, d1), d2);
        if (p == 0) mloc = fmaxf(mloc, d3);           // p==1: c=7 is padding, exclude
        const float m = fmaxf(mloc, __shfl_xor(mloc, 16, 64));
        const float e0 = __builtin_amdgcn_exp2f((d0 - m) * L2E);
        const float e1 = __builtin_amdgcn_exp2f((d1 - m) * L2E);
        const float e2 = __builtin_amdgcn_exp2f((d2 - m) * L2E);
        const float e3 = (p == 0) ? __builtin_amdgcn_exp2f((d3 - m) * L2E) : 0.0f;
        const float sl = e0 + e1 + e2 + e3;
        const float ssum = sl + __shfl_xor(sl, 16, 64);
        const float inv = __builtin_amdgcn_rcpf(ssum);
        if (p < 2) {
            const int bL = wave * 64 + k2 * 16 + q;
            float* dst = sf + bL * CC + p * 4;
            dst[0] = e0 * inv; dst[1] = e1 * inv; dst[2] = e2 * inv;
            if (p == 0) dst[3] = e3 * inv;
        }
    }
    __syncthreads();
    // ---- coalesced writeback ----
    {
        const long long obase = base * CC;
        const long long omax = (long long)Bt * CC;
        #pragma unroll
        for (int i = 0; i < CC; ++i) {
            const long long g = obase + tid + i * BLOCK;
            if (g < omax) out[g] = sf[tid + i * BLOCK];
        }
    }
}

extern "C" void kernel_launch(void* const* d_in, const int* in_sizes, int n_in,
                              void* d_out, int out_size, void* d_ws, size_t ws_size,
                              hipStream_t stream) {
    const float* x  = (const float*)d_in[0];
    const float* k  = (const float*)d_in[1];
    const float* rk = (const float*)d_in[2];
    const float* bi = (const float*)d_in[3];
    const float* dw = (const float*)d_in[4];
    const float* db = (const float*)d_in[5];
    float* out = (float*)d_out;
    float* ws  = (float*)d_ws;

    const int Bt = in_sizes[0] / TF;  // 1048576
    prep_weights<<<1, BLOCK, 0, stream>>>(k, rk, bi, dw, db, ws);
    const int grid = (Bt + BLOCK - 1) / BLOCK;
    gru_main<<<grid, BLOCK, 0, stream>>>(x, ws, out, Bt);
}